// Round 4
// baseline (355.056 us; speedup 1.0000x reference)
//
#include <hip/hip_runtime.h>
#include <hip/hip_fp16.h>
#include <stdint.h>

typedef _Float16 half_t;
typedef __attribute__((ext_vector_type(8))) _Float16 half8;   // MFMA A/B frag (4 VGPRs)
typedef __attribute__((ext_vector_type(16))) float f32x16;    // 32x32 MFMA C/D frag
typedef __attribute__((ext_vector_type(4)))  float float4v;

#define BM 128
#define BN 128
#define BK 64   // 8 chunks of 8 halves (16 B) per row

// ---------------------------------------------------------------------------
// Single fused kernel (stateless, no d_ws — R0's post-timing failure class
// eliminated; R2 coop detour regressed; R3 dbuf+prefetch = 250us dispatch).
//
// R4 change vs R3: the R3 counters showed VGPR_Count=88 < the 128+ needed to
// hold 64 staging floats + 64 acc regs, proving the compiler serialized the
// prefetch (reused a small reg block: load->wait->cvt in chunks), re-exposing
// global-load latency every K-step. Fix:
//   1. __launch_bounds__(256, 2): VGPR cap 256. Residency is LDS-bound at
//      2 blocks/CU (64KB/block), i.e. 2 waves/SIMD, which 256 VGPR still
//      permits -> pure ILP gain, no occupancy loss.
//   2. sched_barrier(0) after the load-issue block so the scheduler cannot
//      sink the staging loads down into the cvt phase (one per K-step, at a
//      phase boundary — the HK placement, not the m141 everywhere-pinning).
//
// K-step (ONE barrier): issue loads(t+1) -> [sched fence] -> MFMA over
// lds[cur] -> cvt+ds_write lds[cur^1] -> barrier.
// Buffer hazard audit unchanged from R3 (one barrier per iter is sufficient).
//
// quantize == fp32->f16 RNE cvt (reference e5m10 quantize incl. denormals),
// applied on stage for A/B and inline for bias.
// GEMM: C[m][n] = sum_k qA[m][k]*qB[n][k] + q(bias[n]); 4 waves (2x2 of
// 64x64), mfma_f32_32x32x16_f16, XOR chunk swizzle on LDS k-chunks,
// XCD-aware block swizzle (4-wide bn strip per XCD, perf-only).
// ---------------------------------------------------------------------------
__global__ __launch_bounds__(256, 2)
void gemm_qf16_dbuf(const float* __restrict__ A, const float* __restrict__ B,
                    const float* __restrict__ bias, float* __restrict__ C,
                    int M, int N, int K) {
    __shared__ half_t sA[2][BM * BK];   // 2 x 16 KB
    __shared__ half_t sB[2][BN * BK];   // 2 x 16 KB

    const int t    = threadIdx.x;
    const int lane = t & 63;
    const int wave = t >> 6;
    const int wm   = (wave >> 1) * 64;
    const int wn   = (wave & 1) * 64;

    // XCD-aware 1-D -> 2-D block swizzle (specialized for the 32x32 grid)
    const int nbx = N / BN, nby = M / BM;
    int bxi, byi;
    {
        const int b = blockIdx.x;
        if (nbx == 32 && nby == 32) {
            const int xcd = b & 7;
            const int s   = b >> 3;
            bxi = xcd * 4 + (s & 3);   // bn strip of 4 per XCD
            byi = s >> 2;
        } else {
            bxi = b % nbx;
            byi = b / nbx;
        }
    }
    const int bm = byi * BM;
    const int bn = bxi * BN;

    // staging: 1024 16B-f16-chunks per matrix per K-step, 4 per thread;
    // chunk c: row = c>>3, LDS pos = c&7, global k-chunk = (c&7) ^ (row&7)
    const float* pa[4];
    const float* pb[4];
    int ldsoff[4];
    #pragma unroll
    for (int s = 0; s < 4; ++s) {
        const int c   = t + 256 * s;
        const int row = c >> 3;
        const int kc  = (c & 7) ^ (row & 7);
        pa[s] = A + (long)(bm + row) * K + kc * 8;
        pb[s] = B + (long)(bn + row) * K + kc * 8;
        ldsoff[s] = c * 8;
    }

    f32x16 acc[2][2] = {};

    const int ml = lane & 31;   // m (or n) within 32-tile
    const int kg = lane >> 5;   // which 8-k half of the MFMA's K=16
    const int sw = ml & 7;      // row component of the XOR swizzle

    // in-flight staging registers (constant-indexed via full unroll)
    float4v ra0[4], ra1[4], rb0[4], rb1[4];

    const int NT = K / BK;

    // ---- prologue: load + cvt + write buf 0 ----
    #pragma unroll
    for (int s = 0; s < 4; ++s) {
        ra0[s] = *(const float4v*)(pa[s]);
        ra1[s] = *(const float4v*)(pa[s] + 4);
        rb0[s] = *(const float4v*)(pb[s]);
        rb1[s] = *(const float4v*)(pb[s] + 4);
        pa[s] += BK; pb[s] += BK;
    }
    #pragma unroll
    for (int s = 0; s < 4; ++s) {
        half8 ha, hb;
        ha[0]=(half_t)ra0[s][0]; ha[1]=(half_t)ra0[s][1]; ha[2]=(half_t)ra0[s][2]; ha[3]=(half_t)ra0[s][3];
        ha[4]=(half_t)ra1[s][0]; ha[5]=(half_t)ra1[s][1]; ha[6]=(half_t)ra1[s][2]; ha[7]=(half_t)ra1[s][3];
        hb[0]=(half_t)rb0[s][0]; hb[1]=(half_t)rb0[s][1]; hb[2]=(half_t)rb0[s][2]; hb[3]=(half_t)rb0[s][3];
        hb[4]=(half_t)rb1[s][0]; hb[5]=(half_t)rb1[s][1]; hb[6]=(half_t)rb1[s][2]; hb[7]=(half_t)rb1[s][3];
        *(half8*)&sA[0][ldsoff[s]] = ha;
        *(half8*)&sB[0][ldsoff[s]] = hb;
    }
    __syncthreads();

    int cur = 0;
    for (int kt = 0; kt < NT; ++kt) {
        const bool more = (kt + 1 < NT);

        // ---- issue next tile's global loads (must stay in flight across
        //      the whole MFMA phase; launch_bounds(256,2) provides the regs) ----
        if (more) {
            #pragma unroll
            for (int s = 0; s < 4; ++s) {
                ra0[s] = *(const float4v*)(pa[s]);
                ra1[s] = *(const float4v*)(pa[s] + 4);
                rb0[s] = *(const float4v*)(pb[s]);
                rb1[s] = *(const float4v*)(pb[s] + 4);
                pa[s] += BK; pb[s] += BK;
            }
        }
        // phase fence: all staging loads issue BEFORE the MFMA phase; the
        // scheduler may not sink them toward their cvt uses.
        __builtin_amdgcn_sched_barrier(0);

        // ---- MFMA phase over lds[cur] ----
        #pragma unroll
        for (int ks = 0; ks < 4; ++ks) {
            const int cp = 2 * ks + kg;                    // k-chunk 0..7
            const int pa0 = ((wm      + ml) * 8 + (cp ^ sw)) * 8;
            const int pa1 = ((wm + 32 + ml) * 8 + (cp ^ sw)) * 8;
            const int pb0 = ((wn      + ml) * 8 + (cp ^ sw)) * 8;
            const int pb1 = ((wn + 32 + ml) * 8 + (cp ^ sw)) * 8;
            half8 a0 = *(const half8*)&sA[cur][pa0];
            half8 a1 = *(const half8*)&sA[cur][pa1];
            half8 b0 = *(const half8*)&sB[cur][pb0];
            half8 b1 = *(const half8*)&sB[cur][pb1];
            acc[0][0] = __builtin_amdgcn_mfma_f32_32x32x16_f16(a0, b0, acc[0][0], 0, 0, 0);
            acc[0][1] = __builtin_amdgcn_mfma_f32_32x32x16_f16(a0, b1, acc[0][1], 0, 0, 0);
            acc[1][0] = __builtin_amdgcn_mfma_f32_32x32x16_f16(a1, b0, acc[1][0], 0, 0, 0);
            acc[1][1] = __builtin_amdgcn_mfma_f32_32x32x16_f16(a1, b1, acc[1][1], 0, 0, 0);
        }

        // ---- cvt + write other buffer (loads drain here, after MFMA) ----
        if (more) {
            const int nxt = cur ^ 1;
            #pragma unroll
            for (int s = 0; s < 4; ++s) {
                half8 ha, hb;
                ha[0]=(half_t)ra0[s][0]; ha[1]=(half_t)ra0[s][1]; ha[2]=(half_t)ra0[s][2]; ha[3]=(half_t)ra0[s][3];
                ha[4]=(half_t)ra1[s][0]; ha[5]=(half_t)ra1[s][1]; ha[6]=(half_t)ra1[s][2]; ha[7]=(half_t)ra1[s][3];
                hb[0]=(half_t)rb0[s][0]; hb[1]=(half_t)rb0[s][1]; hb[2]=(half_t)rb0[s][2]; hb[3]=(half_t)rb0[s][3];
                hb[4]=(half_t)rb1[s][0]; hb[5]=(half_t)rb1[s][1]; hb[6]=(half_t)rb1[s][2]; hb[7]=(half_t)rb1[s][3];
                *(half8*)&sA[nxt][ldsoff[s]] = ha;
                *(half8*)&sB[nxt][ldsoff[s]] = hb;
            }
        }
        __syncthreads();
        cur ^= 1;
    }

    // Epilogue. 32x32 C/D layout [m74/m101]: col = lane&31,
    // row = (reg&3) + 8*(reg>>2) + 4*(lane>>5)
    const int cl = lane & 31;
    const int rb = 4 * (lane >> 5);
    #pragma unroll
    for (int j = 0; j < 2; ++j) {
        const int col = bn + wn + j * 32 + cl;
        const float bq = (float)(half_t)bias[col];   // inline bias quantize
        #pragma unroll
        for (int i = 0; i < 2; ++i) {
            #pragma unroll
            for (int r = 0; r < 16; ++r) {
                const int row = bm + wm + i * 32 + (r & 3) + 8 * (r >> 2) + rb;
                C[(long)row * N + col] = acc[i][j][r] + bq;
            }
        }
    }
}

extern "C" void kernel_launch(void* const* d_in, const int* in_sizes, int n_in,
                              void* d_out, int out_size, void* d_ws, size_t ws_size,
                              hipStream_t stream) {
    const float* x    = (const float*)d_in[0];
    const float* w    = (const float*)d_in[1];
    const float* bias = (const float*)d_in[2];
    float* out = (float*)d_out;

    const int OUT = in_sizes[2];
    const int IN  = in_sizes[1] / OUT;
    const int M   = in_sizes[0] / IN;
    const int N   = OUT, K = IN;

    dim3 grid((N / BN) * (M / BM));
    gemm_qf16_dbuf<<<grid, 256, 0, stream>>>(x, w, bias, out, M, N, K);
    (void)d_ws; (void)ws_size; (void)n_in; (void)out_size;
}

// Round 5
// 350.078 us; speedup vs baseline: 1.0142x; 1.0142x over previous
//
#include <hip/hip_runtime.h>
#include <hip/hip_fp16.h>
#include <stdint.h>

typedef _Float16 half_t;
typedef __attribute__((ext_vector_type(8))) _Float16 half8;   // MFMA A/B frag (4 VGPRs)
typedef __attribute__((ext_vector_type(16))) float f32x16;    // 32x32 MFMA C/D frag
typedef __attribute__((ext_vector_type(4)))  float float4v;

#define BM 128
#define BN 128
#define BK 64   // 8 chunks of 8 halves (16 B) per row

// ---------------------------------------------------------------------------
// R5: force the staging-load schedule (see round notes). Straight-line K-loop
// (last iter peeled), volatile inline-asm global_load_dwordx4 staging with
// "=&v" outputs pinned live across the MFMA phase, explicit
// s_waitcnt vmcnt(0) + sched_barrier(0) before the cvt block.
// K-step: issue loads(t+1) -> fence -> 16 MFMA over lds[cur] -> vmcnt(0)
// -> cvt+ds_write lds[cur^1] -> barrier. One barrier per step.
// quantize == fp32->f16 RNE cvt; bias quantized inline in epilogue.
// ---------------------------------------------------------------------------
__global__ __launch_bounds__(256, 2)
void gemm_qf16_pipe(const float* __restrict__ A, const float* __restrict__ B,
                    const float* __restrict__ bias, float* __restrict__ C,
                    int M, int N, int K) {
    __shared__ half_t sA[2][BM * BK];   // 2 x 16 KB
    __shared__ half_t sB[2][BN * BK];   // 2 x 16 KB

    const int t    = threadIdx.x;
    const int lane = t & 63;
    const int wave = t >> 6;
    const int wm   = (wave >> 1) * 64;
    const int wn   = (wave & 1) * 64;

    const int nbx = N / BN, nby = M / BM;
    int bxi, byi;
    {
        const int b = blockIdx.x;
        if (nbx == 32 && nby == 32) {
            const int xcd = b & 7;
            const int s   = b >> 3;
            bxi = xcd * 4 + (s & 3);   // bn strip of 4 per XCD
            byi = s >> 2;
        } else {
            bxi = b % nbx;
            byi = b / nbx;
        }
    }
    const int bm = byi * BM;
    const int bn = bxi * BN;

    const float* pa[4];
    const float* pb[4];
    int ldsoff[4];
    #pragma unroll
    for (int s = 0; s < 4; ++s) {
        const int c   = t + 256 * s;
        const int row = c >> 3;
        const int kc  = (c & 7) ^ (row & 7);
        pa[s] = A + (long)(bm + row) * K + kc * 8;
        pb[s] = B + (long)(bn + row) * K + kc * 8;
        ldsoff[s] = c * 8;
    }

    f32x16 acc[2][2] = {};

    const int ml = lane & 31;   // m (or n) within 32-tile
    const int kg = lane >> 5;   // which 8-k half of the MFMA's K=16
    const int sw = ml & 7;      // row component of the XOR swizzle

    float4v ra0[4], ra1[4], rb0[4], rb1[4];

    const int NT = K / BK;

    // ---- prologue: synchronous load + cvt + write buf 0 ----
    #pragma unroll
    for (int s = 0; s < 4; ++s) {
        ra0[s] = *(const float4v*)(pa[s]);
        ra1[s] = *(const float4v*)(pa[s] + 4);
        rb0[s] = *(const float4v*)(pb[s]);
        rb1[s] = *(const float4v*)(pb[s] + 4);
        pa[s] += BK; pb[s] += BK;
    }
    #pragma unroll
    for (int s = 0; s < 4; ++s) {
        half8 ha, hb;
        ha[0]=(half_t)ra0[s][0]; ha[1]=(half_t)ra0[s][1]; ha[2]=(half_t)ra0[s][2]; ha[3]=(half_t)ra0[s][3];
        ha[4]=(half_t)ra1[s][0]; ha[5]=(half_t)ra1[s][1]; ha[6]=(half_t)ra1[s][2]; ha[7]=(half_t)ra1[s][3];
        hb[0]=(half_t)rb0[s][0]; hb[1]=(half_t)rb0[s][1]; hb[2]=(half_t)rb0[s][2]; hb[3]=(half_t)rb0[s][3];
        hb[4]=(half_t)rb1[s][0]; hb[5]=(half_t)rb1[s][1]; hb[6]=(half_t)rb1[s][2]; hb[7]=(half_t)rb1[s][3];
        *(half8*)&sA[0][ldsoff[s]] = ha;
        *(half8*)&sB[0][ldsoff[s]] = hb;
    }
    __syncthreads();

    int cur = 0;
    for (int kt = 0; kt < NT - 1; ++kt) {
        #pragma unroll
        for (int s = 0; s < 4; ++s) {
            asm volatile("global_load_dwordx4 %0, %2, off\n\t"
                         "global_load_dwordx4 %1, %2, off offset:16"
                         : "=&v"(ra0[s]), "=&v"(ra1[s])
                         : "v"(pa[s])
                         : "memory");
            asm volatile("global_load_dwordx4 %0, %2, off\n\t"
                         "global_load_dwordx4 %1, %2, off offset:16"
                         : "=&v"(rb0[s]), "=&v"(rb1[s])
                         : "v"(pb[s])
                         : "memory");
            pa[s] += BK; pb[s] += BK;
        }
        __builtin_amdgcn_sched_barrier(0);

        #pragma unroll
        for (int ks = 0; ks < 4; ++ks) {
            const int cp = 2 * ks + kg;                    // k-chunk 0..7
            const int qa0 = ((wm      + ml) * 8 + (cp ^ sw)) * 8;
            const int qa1 = ((wm + 32 + ml) * 8 + (cp ^ sw)) * 8;
            const int qb0 = ((wn      + ml) * 8 + (cp ^ sw)) * 8;
            const int qb1 = ((wn + 32 + ml) * 8 + (cp ^ sw)) * 8;
            half8 a0 = *(const half8*)&sA[cur][qa0];
            half8 a1 = *(const half8*)&sA[cur][qa1];
            half8 b0 = *(const half8*)&sB[cur][qb0];
            half8 b1 = *(const half8*)&sB[cur][qb1];
            acc[0][0] = __builtin_amdgcn_mfma_f32_32x32x16_f16(a0, b0, acc[0][0], 0, 0, 0);
            acc[0][1] = __builtin_amdgcn_mfma_f32_32x32x16_f16(a0, b1, acc[0][1], 0, 0, 0);
            acc[1][0] = __builtin_amdgcn_mfma_f32_32x32x16_f16(a1, b0, acc[1][0], 0, 0, 0);
            acc[1][1] = __builtin_amdgcn_mfma_f32_32x32x16_f16(a1, b1, acc[1][1], 0, 0, 0);
        }

        asm volatile("s_waitcnt vmcnt(0)" ::: "memory");
        __builtin_amdgcn_sched_barrier(0);   // rule #18: no cvt hoisting
        {
            const int nxt = cur ^ 1;
            #pragma unroll
            for (int s = 0; s < 4; ++s) {
                half8 ha, hb;
                ha[0]=(half_t)ra0[s][0]; ha[1]=(half_t)ra0[s][1]; ha[2]=(half_t)ra0[s][2]; ha[3]=(half_t)ra0[s][3];
                ha[4]=(half_t)ra1[s][0]; ha[5]=(half_t)ra1[s][1]; ha[6]=(half_t)ra1[s][2]; ha[7]=(half_t)ra1[s][3];
                hb[0]=(half_t)rb0[s][0]; hb[1]=(half_t)rb0[s][1]; hb[2]=(half_t)rb0[s][2]; hb[3]=(half_t)rb0[s][3];
                hb[4]=(half_t)rb1[s][0]; hb[5]=(half_t)rb1[s][1]; hb[6]=(half_t)rb1[s][2]; hb[7]=(half_t)rb1[s][3];
                *(half8*)&sA[nxt][ldsoff[s]] = ha;
                *(half8*)&sB[nxt][ldsoff[s]] = hb;
            }
        }
        __syncthreads();
        cur ^= 1;
    }

    // ---- final tile: MFMA only ----
    #pragma unroll
    for (int ks = 0; ks < 4; ++ks) {
        const int cp = 2 * ks + kg;
        const int qa0 = ((wm      + ml) * 8 + (cp ^ sw)) * 8;
        const int qa1 = ((wm + 32 + ml) * 8 + (cp ^ sw)) * 8;
        const int qb0 = ((wn      + ml) * 8 + (cp ^ sw)) * 8;
        const int qb1 = ((wn + 32 + ml) * 8 + (cp ^ sw)) * 8;
        half8 a0 = *(const half8*)&sA[cur][qa0];
        half8 a1 = *(const half8*)&sA[cur][qa1];
        half8 b0 = *(const half8*)&sB[cur][qb0];
        half8 b1 = *(const half8*)&sB[cur][qb1];
        acc[0][0] = __builtin_amdgcn_mfma_f32_32x32x16_f16(a0, b0, acc[0][0], 0, 0, 0);
        acc[0][1] = __builtin_amdgcn_mfma_f32_32x32x16_f16(a0, b1, acc[0][1], 0, 0, 0);
        acc[1][0] = __builtin_amdgcn_mfma_f32_32x32x16_f16(a1, b0, acc[1][0], 0, 0, 0);
        acc[1][1] = __builtin_amdgcn_mfma_f32_32x32x16_f16(a1, b1, acc[1][1], 0, 0, 0);
    }

    const int cl = lane & 31;
    const int rb = 4 * (lane >> 5);
    #pragma unroll
    for (int j = 0; j < 2; ++j) {
        const int col = bn + wn + j * 32 + cl;
        const float bq = (float)(half_t)bias[col];   // inline bias quantize
        #pragma unroll
        for (int i = 0; i < 2; ++i) {
            #pragma unroll
            for (int r = 0; r < 16; ++r) {
                const int row = bm + wm + i * 32 + (r & 3) + 8 * (r >> 2) + rb;
                C[(long)row * N + col] = acc[i][j][r] + bq;
            }
        }
    }
}

extern "C" void kernel_launch(void* const* d_in, const int* in_sizes, int n_in,
                              void* d_out, int out_size, void* d_ws, size_t ws_size,
                              hipStream_t stream) {
    const float* x    = (const float*)d_in[0];
    const float* w    = (const float*)d_in[1];
    const float* bias = (const float*)d_in[2];
    float* out = (float*)d_out;

    const int OUT = in_sizes[2];
    const int IN  = in_sizes[1] / OUT;
    const int M   = in_sizes[0] / IN;
    const int N   = OUT, K = IN;

    dim3 grid((N / BN) * (M / BM));
    gemm_qf16_pipe<<<grid, 256, 0, stream>>>(x, w, bias, out, M, N, K);
    (void)d_ws; (void)ws_size; (void)n_in; (void)out_size;
}